// Round 1
// 212.404 us; speedup vs baseline: 1.1529x; 1.1529x over previous
//
#include <hip/hip_runtime.h>
#include <stdint.h>

// GumbelVQ forward, MI355X — round 17: asm-pinned threefry + 4 rows/block +
// fused histogram.
//
// Theory: R12/R16 argmax is VALU-issue-bound (VALUBusy ~90%, MFMA 0, HBM 0.4%)
// but runs ~2x over the hand-counted instruction floor. This round pins the
// threefry core with inline asm (4 interleaved chains, v_alignbit rotates,
// v_add3_u32 key-injection folds, hand-folded round 1 since x0_init==0),
// amortizes proj_w loads over 4 rows, and fuses the code histogram into the
// argmax kernel (device-global atomics) so the stats kernel is a pure
// 8192-bin entropy pass.
//
//   d_out (float[73731]):
//     [0..65535]     z_q f32 (B,D,H,W)          — argmax epilogue
//     [65536..73727] indices as f32 values      — argmax epilogue
//     [73728..73730] commit, perplexity, usage  — 73728 doubles as commit accum
// Inputs (float32): z_e (8,8,32,32), embedding (8192,8), proj_w (8192,8).

#define NCODES 8192
#define NROWS  8192

__device__ int g_hist[NCODES];

// ---------------- threefry-2x32, key (0,42), 4 interleaved chains ----------
// Counter for (row n, code k) is c = n*8192 + k (hi word = 0). JAX
// partitionable path: bits = o0 ^ o1 of threefry((0,42), (0, c)).
// Inputs %8..%11 must hold c + 42 (ks1 pre-added). Outputs %0..%3 = o0^o1.
// rotl(x,r) == v_alignbit_b32(x, x, 32-r).
// Round schedule: [13,15,26,6] [17,29,16,24] x alternating, 5 groups;
// injections after group g: x0 += ks[g%3], x1 += ks[(g+1)%3] + g,
// ks = {0, 42, 0x1BD11BF0}.

#define TF4_R1 \
  "v_mov_b32 %4, %8\n" "v_mov_b32 %5, %9\n" \
  "v_mov_b32 %6, %10\n" "v_mov_b32 %7, %11\n" \
  "v_alignbit_b32 %0, %8, %8, 19\n" "v_alignbit_b32 %1, %9, %9, 19\n" \
  "v_alignbit_b32 %2, %10, %10, 19\n" "v_alignbit_b32 %3, %11, %11, 19\n" \
  "v_xor_b32 %0, %0, %4\n" "v_xor_b32 %1, %1, %5\n" \
  "v_xor_b32 %2, %2, %6\n" "v_xor_b32 %3, %3, %7\n"

#define TF4_ADD \
  "v_add_u32 %4, %4, %0\n" "v_add_u32 %5, %5, %1\n" \
  "v_add_u32 %6, %6, %2\n" "v_add_u32 %7, %7, %3\n"

#define TF4_ADD3_42 \
  "v_add3_u32 %4, %4, %0, 42\n" "v_add3_u32 %5, %5, %1, 42\n" \
  "v_add3_u32 %6, %6, %2, 42\n" "v_add3_u32 %7, %7, %3, 42\n"

#define TF4_ROT(s) \
  "v_alignbit_b32 %0, %0, %0, " #s "\n" "v_alignbit_b32 %1, %1, %1, " #s "\n" \
  "v_alignbit_b32 %2, %2, %2, " #s "\n" "v_alignbit_b32 %3, %3, %3, " #s "\n"

#define TF4_XOR \
  "v_xor_b32 %0, %0, %4\n" "v_xor_b32 %1, %1, %5\n" \
  "v_xor_b32 %2, %2, %6\n" "v_xor_b32 %3, %3, %7\n"

#define TF4_AX1(lit) \
  "v_add_u32 %0, " #lit ", %0\n" "v_add_u32 %1, " #lit ", %1\n" \
  "v_add_u32 %2, " #lit ", %2\n" "v_add_u32 %3, " #lit ", %3\n"

#define TF4_AX0(lit) \
  "v_add_u32 %4, " #lit ", %4\n" "v_add_u32 %5, " #lit ", %5\n" \
  "v_add_u32 %6, " #lit ", %6\n" "v_add_u32 %7, " #lit ", %7\n"

#define TF4_RN(s)  TF4_ADD     TF4_ROT(s) TF4_XOR
#define TF4_RN3(s) TF4_ADD3_42 TF4_ROT(s) TF4_XOR

// gumbel = -ln(-ln u) = C - ln2*log2(-log2 u), C = -ln2*log2(ln2).
#define GVQ_C   0.36651292058166435f
#define GVQ_LN2 0.69314718055994530942f
__device__ __forceinline__ float gvq17_gumbel(uint32_t bits) {
    float u = __uint_as_float((bits >> 9) | 0x3f800000u) - 1.0f;
    float l1 = __builtin_amdgcn_logf(u);            // log2(u) <= 0
    float l2 = __builtin_amdgcn_logf(0.0f - l1);    // log2(-log2 u)
    return fmaf(-GVQ_LN2, l2, GVQ_C);
}

__global__ __launch_bounds__(1024) void gvq17_init(float* out) {
    const int t = threadIdx.x;
    for (int k = t; k < NCODES; k += 1024) g_hist[k] = 0;
    if (t == 0) out[73728] = 0.0f;                  // commit accumulator
}

#define DOT8(zz) \
    fmaf(zz[7], wb.w, fmaf(zz[6], wb.z, fmaf(zz[5], wb.y, fmaf(zz[4], wb.x, \
    fmaf(zz[3], wa.w, fmaf(zz[2], wa.z, fmaf(zz[1], wa.y, zz[0] * wa.x)))))))

// Kernel 1: 4 rows/block, 256 threads, k-stride 256 (32 iterations).
__global__ __launch_bounds__(256, 5) void gvq17_argmax(const float* __restrict__ z_e,
                                                       const float* __restrict__ proj_w,
                                                       const float* __restrict__ emb,
                                                       float* __restrict__ out) {
    __shared__ float sv[4][256];
    __shared__ int   sj[4][256];
    __shared__ float ssq[4];
    const int tid = threadIdx.x;
    const int n0 = blockIdx.x * 4;                  // rows n0..n0+3

    float z0[8], z1[8], z2[8], z3[8];
    {
        const int b = n0 >> 10, r = n0 & 1023;      // rows n0..n0+3 share b? no:
        (void)b; (void)r;
    }
#pragma unroll
    for (int d = 0; d < 8; ++d) {
        const int nA = n0 + 0, nB = n0 + 1, nC = n0 + 2, nD = n0 + 3;
        z0[d] = z_e[(nA >> 10) * 8192 + d * 1024 + (nA & 1023)];
        z1[d] = z_e[(nB >> 10) * 8192 + d * 1024 + (nB & 1023)];
        z2[d] = z_e[(nC >> 10) * 8192 + d * 1024 + (nC & 1023)];
        z3[d] = z_e[(nD >> 10) * 8192 + d * 1024 + (nD & 1023)];
    }

    // counters with ks1 (=42) pre-added
    uint32_t ca = ((uint32_t)(n0 + 0) << 13) + (uint32_t)tid + 42u;
    uint32_t cb = ((uint32_t)(n0 + 1) << 13) + (uint32_t)tid + 42u;
    uint32_t cc = ((uint32_t)(n0 + 2) << 13) + (uint32_t)tid + 42u;
    uint32_t cd = ((uint32_t)(n0 + 3) << 13) + (uint32_t)tid + 42u;

    const float4* p = ((const float4*)proj_w) + 2 * tid;
    float best0 = -INFINITY, best1 = -INFINITY, best2 = -INFINITY, best3 = -INFINITY;
    int bi0 = 0, bi1 = 0, bi2 = 0, bi3 = 0;
    int k = tid;

    for (int i = 0; i < 32; ++i) {
        float4 wa = p[0];
        float4 wb = p[1];
        p += 512;                                   // 256 codes * 2 float4

        float d0 = DOT8(z0);
        float d1 = DOT8(z1);
        float d2 = DOT8(z2);
        float d3 = DOT8(z3);

        uint32_t o0, o1, o2, o3, t0, t1, t2, t3;
        asm(TF4_R1                                   // G1: rot 13,15,26,6
            TF4_RN(17) TF4_RN(6) TF4_RN(26)
            TF4_AX1(0x1BD11BF1)                      // x1 += ks2+1
            TF4_RN3(15) TF4_RN(3) TF4_RN(16) TF4_RN(8)  // G2 (x0+=42 folded)
            TF4_AX0(0x1BD11BF0) TF4_AX1(2)           // x0 += ks2; x1 += 2
            TF4_RN(19) TF4_RN(17) TF4_RN(6) TF4_RN(26)  // G3 (x0+=0 free)
            TF4_AX1(45)                              // x1 += 45
            TF4_RN(15) TF4_RN(3) TF4_RN(16) TF4_RN(8)   // G4
            TF4_AX1(0x1BD11BF4)                      // x1 += ks2+4
            TF4_RN3(19) TF4_RN(17) TF4_RN(6) TF4_RN(26) // G5 (x0+=42 folded)
            TF4_AX0(0x1BD11BF0) TF4_AX1(5)           // final x0 += ks2; x1 += 5
            TF4_XOR                                  // out = x1 ^ x0
            : "=&v"(o0), "=&v"(o1), "=&v"(o2), "=&v"(o3),
              "=&v"(t0), "=&v"(t1), "=&v"(t2), "=&v"(t3)
            : "v"(ca), "v"(cb), "v"(cc), "v"(cd));
        (void)t0; (void)t1; (void)t2; (void)t3;

        float v0 = d0 + gvq17_gumbel(o0);
        float v1 = d1 + gvq17_gumbel(o1);
        float v2 = d2 + gvq17_gumbel(o2);
        float v3 = d3 + gvq17_gumbel(o3);

        if (v0 > best0) { best0 = v0; bi0 = k; }    // strict > : first max wins
        if (v1 > best1) { best1 = v1; bi1 = k; }
        if (v2 > best2) { best2 = v2; bi2 = k; }
        if (v3 > best3) { best3 = v3; bi3 = k; }

        ca += 256u; cb += 256u; cc += 256u; cd += 256u;
        k += 256;
    }

    sv[0][tid] = best0; sj[0][tid] = bi0;
    sv[1][tid] = best1; sj[1][tid] = bi1;
    sv[2][tid] = best2; sj[2][tid] = bi2;
    sv[3][tid] = best3; sj[3][tid] = bi3;
    __syncthreads();
    for (int s = 128; s > 0; s >>= 1) {
        if (tid < s) {
#pragma unroll
            for (int r = 0; r < 4; ++r) {
                float va = sv[r][tid + s];
                if (va > sv[r][tid] ||
                    (va == sv[r][tid] && sj[r][tid + s] < sj[r][tid])) {
                    sv[r][tid] = va; sj[r][tid] = sj[r][tid + s];
                }
            }
        }
        __syncthreads();
    }

    if (tid < 4) {
        const int n = n0 + tid;
        const int idx = sj[tid][0];
        out[65536 + n] = (float)idx;
        atomicAdd(&g_hist[idx], 1);
        float zz[8];
#pragma unroll
        for (int d = 0; d < 8; ++d) {
            zz[d] = (tid == 0) ? z0[d] : (tid == 1) ? z1[d]
                  : (tid == 2) ? z2[d] : z3[d];
        }
        const float4* ep = (const float4*)(emb + idx * 8);
        float4 ea = ep[0], eb = ep[1];
        float e[8] = {ea.x, ea.y, ea.z, ea.w, eb.x, eb.y, eb.z, eb.w};
        const int b = n >> 10, r = n & 1023;
        float sq = 0.0f;
#pragma unroll
        for (int d = 0; d < 8; ++d) {
            out[b * 8192 + d * 1024 + r] = e[d];     // z_q (B,D,H,W)
            float diff = zz[d] - e[d];
            sq = fmaf(diff, diff, sq);
        }
        ssq[tid] = sq;
    }
    __syncthreads();
    if (tid == 0)
        atomicAdd(out + 73728, ssq[0] + ssq[1] + ssq[2] + ssq[3]);
}

// Kernel 2: single block, 1024 threads. Entropy/usage straight from g_hist;
// finalize commit from accumulated sum.
__global__ __launch_bounds__(1024) void gvq17_stats(float* __restrict__ out) {
    __shared__ float hred[1024];
    __shared__ int   ired[1024];
    const int tid = threadIdx.x;

    float h = 0.0f; int used = 0;
    for (int kk = tid; kk < NCODES; kk += 1024) {
        int c = g_hist[kk];
        float avg = (float)c * (1.0f / 8192.0f);
        h += avg * logf(avg + 1e-10f);               // accurate: 8 iters/thread
        used += (c > 0) ? 1 : 0;
    }
    hred[tid] = h; ired[tid] = used;
    __syncthreads();
    for (int t = 512; t > 0; t >>= 1) {
        if (tid < t) { hred[tid] += hred[tid + t]; ired[tid] += ired[tid + t]; }
        __syncthreads();
    }
    if (tid == 0) {
        float accum = out[73728];
        out[73728] = 0.25f * accum * (1.0f / 65536.0f);   // commit loss
        out[73729] = expf(-hred[0]);                      // perplexity
        out[73730] = (float)ired[0] * (1.0f / 8192.0f);   // usage
    }
}

extern "C" void kernel_launch(void* const* d_in, const int* in_sizes, int n_in,
                              void* d_out, int out_size, void* d_ws, size_t ws_size,
                              hipStream_t stream) {
    const float* z_e   = (const float*)d_in[0];
    const float* emb   = (const float*)d_in[1];
    const float* projw = (const float*)d_in[2];
    float* out = (float*)d_out;

    gvq17_init  <<<1,    1024, 0, stream>>>(out);
    gvq17_argmax<<<2048, 256,  0, stream>>>(z_e, projw, emb, out);
    gvq17_stats <<<1,    1024, 0, stream>>>(out);
}